// Round 1
// baseline (272.701 us; speedup 1.0000x reference)
//
#include <hip/hip_runtime.h>
#include <math.h>

// Problem: Z = Q_F (D * (Q_F^T X Q_S)) Q_S^T  ==  solve (I - gamma*lam_j*G) y_j = (X Q_S)_j ; Z = Y Q_S^T
// G = F^T F / (||F^T F||_F + 1e-12), spectral radius of gamma*lam*G bounded by 0.76.
// (I - aG)^-1 approx= prod_{j=0..4} (I + a^(2^j) * G^(2^j))  (exact 31-term Neumann sum).

#define KSPLIT 8
#define KCHUNK (4096 / KSPLIT)  // 512

constexpr int Mdim = 64;
constexpr int Ndim = 4096;

// ---------------- Stage A: G and its powers G^2, G^4, G^8, G^16 -------------
__global__ __launch_bounds__(256) void prep_kernel(const float* __restrict__ F,
                                                   float* __restrict__ Gout) {
    __shared__ float A[4096];
    __shared__ float B[4096];
    __shared__ float red[256];
    const int t = threadIdx.x;
    // FF = F^T F  (F is 64x64 row-major)
    for (int e = t; e < 4096; e += 256) {
        const int a = e >> 6, b = e & 63;
        float s = 0.f;
        for (int k = 0; k < 64; ++k) s += F[k * 64 + a] * F[k * 64 + b];
        A[e] = s;
    }
    __syncthreads();
    float ss = 0.f;
    for (int e = t; e < 4096; e += 256) ss += A[e] * A[e];
    red[t] = ss;
    __syncthreads();
    for (int off = 128; off > 0; off >>= 1) {
        if (t < off) red[t] += red[t + off];
        __syncthreads();
    }
    const float inv = 1.0f / (sqrtf(red[0]) + 1e-12f);
    __syncthreads();
    for (int e = t; e < 4096; e += 256) {
        const float g = A[e] * inv;
        A[e] = g;
        Gout[e] = g;
    }
    __syncthreads();
    float* src = A;
    float* dst = B;
    for (int j = 1; j < 5; ++j) {
        for (int e = t; e < 4096; e += 256) {
            const int r = e >> 6, c = e & 63;
            float s = 0.f;
            for (int k = 0; k < 64; ++k) s += src[r * 64 + k] * src[k * 64 + c];
            dst[e] = s;
        }
        __syncthreads();
        for (int e = t; e < 4096; e += 256) Gout[j * 4096 + e] = dst[e];
        float* tmp = src; src = dst; dst = tmp;
        __syncthreads();
    }
}

// ---------------- Stages B/D: C += A(64x4096) @ B-tile -----------------------
// TB=false: C = A @ Bm          (Bm row-major KxN, used as X @ Q_S)
// TB=true : C = A @ Bm^T        (Bm row-major NxK layout Qs[t*4096+j], Y @ Q_S^T)
// Grid: (4096/64 n-tiles, KSPLIT k-chunks). fp32 atomicAdd into zeroed C.
template <bool TB>
__global__ __launch_bounds__(256) void gemm_kernel(const float* __restrict__ A,
                                                   const float* __restrict__ Bm,
                                                   float* __restrict__ C) {
    __shared__ float As[16][68];  // [kk][m], padded: 16B-aligned rows, no 4-way conflicts
    __shared__ float Bs[16][68];  // [kk][n]
    const int t = threadIdx.x;
    const int n0 = blockIdx.x * 64;
    const int kbase = blockIdx.y * KCHUNK;
    const int tx = t & 15, ty = t >> 4;
    const int am = t >> 2;            // row 0..63
    const int ak = (t & 3) * 4;       // 4 consecutive k
    float acc[4][4] = {};

    for (int kt = 0; kt < KCHUNK; kt += 16) {
        const int k0 = kbase + kt;
        const float4 av = *(const float4*)&A[am * 4096 + k0 + ak];
        float4 bv;
        if (TB) {
            bv = *(const float4*)&Bm[(n0 + am) * 4096 + k0 + ak];
        } else {
            bv = *(const float4*)&Bm[(size_t)(k0 + (t >> 4)) * 4096 + n0 + (t & 15) * 4];
        }
        __syncthreads();
        As[ak + 0][am] = av.x; As[ak + 1][am] = av.y;
        As[ak + 2][am] = av.z; As[ak + 3][am] = av.w;
        if (TB) {
            Bs[ak + 0][am] = bv.x; Bs[ak + 1][am] = bv.y;
            Bs[ak + 2][am] = bv.z; Bs[ak + 3][am] = bv.w;
        } else {
            *(float4*)&Bs[t >> 4][(t & 15) * 4] = bv;
        }
        __syncthreads();
#pragma unroll
        for (int kk = 0; kk < 16; ++kk) {
            const float4 a = *(const float4*)&As[kk][ty * 4];
            const float4 b = *(const float4*)&Bs[kk][tx * 4];
            const float ar[4] = {a.x, a.y, a.z, a.w};
            const float br[4] = {b.x, b.y, b.z, b.w};
#pragma unroll
            for (int i = 0; i < 4; ++i)
#pragma unroll
                for (int j = 0; j < 4; ++j) acc[i][j] += ar[i] * br[j];
        }
    }
    const int cb = n0 + tx * 4;
#pragma unroll
    for (int i = 0; i < 4; ++i)
#pragma unroll
        for (int j = 0; j < 4; ++j)
            atomicAdd(&C[(ty * 4 + i) * 4096 + cb + j], acc[i][j]);
}

// ---------------- Stage C: per-column solve via squaring product -------------
// T <- T + a^(2^j) * (G_j @ T), j = 0..4 ; a = gamma * lambda_col
__global__ __launch_bounds__(256) void solve_kernel(const float* __restrict__ W,
                                                    const float* __restrict__ Gp,
                                                    const float* __restrict__ lam,
                                                    const float* __restrict__ gammap,
                                                    float* __restrict__ Y) {
    __shared__ float Gs[64][68];  // G_j, symmetric: Gs[k][r] == G_j[r][k]
    __shared__ float T[64][17];   // 64 rows x 16 columns
    const int t = threadIdx.x;
    const int c0 = blockIdx.x * 16;
    for (int e = t; e < 1024; e += 256)
        T[e >> 4][e & 15] = W[(e >> 4) * 4096 + c0 + (e & 15)];
    const int tx = t & 15;
    const int r4 = (t >> 4) * 4;
    const float a = gammap[0] * lam[c0 + tx];
    float s = a;
    for (int j = 0; j < 5; ++j) {
        __syncthreads();  // prior T update + prior Gs reads complete
        for (int e = t; e < 4096; e += 256) Gs[e >> 6][e & 63] = Gp[j * 4096 + e];
        __syncthreads();
        float u0 = 0.f, u1 = 0.f, u2 = 0.f, u3 = 0.f;
#pragma unroll 8
        for (int k = 0; k < 64; ++k) {
            const float tv = T[k][tx];
            const float4 g = *(const float4*)&Gs[k][r4];
            u0 += g.x * tv; u1 += g.y * tv; u2 += g.z * tv; u3 += g.w * tv;
        }
        __syncthreads();  // everyone done reading T
        T[r4 + 0][tx] += s * u0;
        T[r4 + 1][tx] += s * u1;
        T[r4 + 2][tx] += s * u2;
        T[r4 + 3][tx] += s * u3;
        s = s * s;
    }
    __syncthreads();
    for (int e = t; e < 1024; e += 256)
        Y[(e >> 4) * 4096 + c0 + (e & 15)] = T[e >> 4][e & 15];
}

extern "C" void kernel_launch(void* const* d_in, const int* in_sizes, int n_in,
                              void* d_out, int out_size, void* d_ws, size_t ws_size,
                              hipStream_t stream) {
    const float* X     = (const float*)d_in[0];  // (64, 4096)
    const float* F     = (const float*)d_in[1];  // (64, 64)
    const float* Qs    = (const float*)d_in[2];  // (4096, 4096)
    const float* lam   = (const float*)d_in[3];  // (4096,)
    const float* gamma = (const float*)d_in[4];  // scalar
    float* Z = (float*)d_out;                    // (64, 4096)

    float* W  = (float*)d_ws;          // 64*4096 floats
    float* Y  = W + Mdim * Ndim;       // 64*4096 floats
    float* Gp = Y + Mdim * Ndim;       // 5 * 64*64 floats

    hipMemsetAsync(W, 0, Mdim * Ndim * sizeof(float), stream);
    hipMemsetAsync(Z, 0, Mdim * Ndim * sizeof(float), stream);

    prep_kernel<<<1, 256, 0, stream>>>(F, Gp);
    gemm_kernel<false><<<dim3(Ndim / 64, KSPLIT), 256, 0, stream>>>(X, Qs, W);
    solve_kernel<<<Ndim / 16, 256, 0, stream>>>(W, Gp, lam, gamma, Y);
    gemm_kernel<true><<<dim3(Ndim / 64, KSPLIT), 256, 0, stream>>>(Y, Qs, Z);
}

// Round 2
// 163.465 us; speedup vs baseline: 1.6683x; 1.6683x over previous
//
#include <hip/hip_runtime.h>
#include <math.h>

// Z = Q_F (D * (Q_F^T X Q_S)) Q_S^T  ==  per-column solve (I - g*lam_j*G) y_j = (X Q_S)_j ; Z = Y Q_S^T
// (I - aG)^-1 = prod_{j=0..4} (I + a^(2^j) G^(2^j))  (exact 31-term Neumann sum; rho <= 0.76)
// GEMMs use bf16 MFMA with hi/lo split (3 products) => fp32-level accuracy, memory-bound.

typedef short short8 __attribute__((ext_vector_type(8)));
typedef float floatx16 __attribute__((ext_vector_type(16)));

#define KSPLIT 8
#define KCHUNK 512
constexpr int Mdim = 64;
constexpr int Ndim = 4096;

__device__ inline ushort f2bf(float f) {
    uint u = __float_as_uint(f);
    u += 0x7fff + ((u >> 16) & 1);  // RNE
    return (ushort)(u >> 16);
}
__device__ inline float bf2f(ushort h) { return __uint_as_float(((uint)h) << 16); }

__device__ inline floatx16 mfma_bf16(short8 a, short8 b, floatx16 c) {
    return __builtin_amdgcn_mfma_f32_32x32x16_bf16(a, b, c, 0, 0, 0);
}

// LDS plane layout (bf16, 64x64 tile): elem (r,k) at r*64 + ((k>>3)^(r&7))*8 + (k&7).
// Granule-XOR swizzle keeps b128 frag reads and transposed writes bank-balanced.

// ---------------- prep: G, G^2, G^4, G^8, G^16 via split-bf16 MFMA ----------
__global__ __launch_bounds__(256) void prep_kernel(const float* __restrict__ F,
                                                   float* __restrict__ Gout) {
    __shared__ float Fraw[64 * 65];
    __shared__ ushort Ph[64 * 64];
    __shared__ ushort Pl[64 * 64];
    __shared__ float red[256];
    const int t = threadIdx.x;
    const int l = t & 63, w = t >> 6;
    const int tm = w & 1, tn = w >> 1;
    const int am = tm * 32 + (l & 31);
    const int bn = tn * 32 + (l & 31);
    const int lk = l >> 5;

    // load F (64x64) into padded LDS
    for (int s = 0; s < 4; ++s) {
        int e = t + 256 * s;
        int r = e >> 4, q = (e & 15) * 4;
        float4 v = *(const float4*)&F[r * 64 + q];
        float fa[4] = {v.x, v.y, v.z, v.w};
        for (int i = 0; i < 4; ++i) Fraw[r * 65 + q + i] = fa[i];
    }
    __syncthreads();
    // transpose into planes: P[c][k] = F[k][c]  (both mfma operands need F^T rows)
    {
        int c = t >> 2, kbase = (t & 3) * 16;
        ushort hh[16], ll[16];
        for (int kk = 0; kk < 16; ++kk) {
            float v = Fraw[(kbase + kk) * 65 + c];
            ushort h = f2bf(v);
            hh[kk] = h;
            ll[kk] = f2bf(v - bf2f(h));
        }
        for (int g = 0; g < 2; ++g) {
            int gk = (kbase >> 3) + g;
            int idx = c * 64 + ((gk ^ (c & 7)) * 8);
            for (int u = 0; u < 8; ++u) { Ph[idx + u] = hh[8 * g + u]; Pl[idx + u] = ll[8 * g + u]; }
        }
    }
    __syncthreads();
    // FF = F^T F
    floatx16 acc;
    for (int i = 0; i < 16; ++i) acc[i] = 0.f;
    for (int s16 = 0; s16 < 4; ++s16) {
        int gk = 2 * s16 + lk;
        int ai = am * 64 + ((gk ^ (am & 7)) * 8);
        int bi = bn * 64 + ((gk ^ (bn & 7)) * 8);
        short8 ah = *(const short8*)&Ph[ai];
        short8 al = *(const short8*)&Pl[ai];
        short8 bh = *(const short8*)&Ph[bi];
        short8 bl = *(const short8*)&Pl[bi];
        acc = mfma_bf16(ah, bh, acc);
        acc = mfma_bf16(al, bh, acc);
        acc = mfma_bf16(ah, bl, acc);
    }
    // Frobenius norm
    float ss = 0.f;
    for (int r = 0; r < 16; ++r) ss += acc[r] * acc[r];
    red[t] = ss;
    __syncthreads();
    for (int off = 128; off > 0; off >>= 1) {
        if (t < off) red[t] += red[t + off];
        __syncthreads();
    }
    const float inv = 1.0f / (sqrtf(red[0]) + 1e-12f);
    // G = FF * inv -> Gout[0] + planes (mfma reads already fenced by reduce barriers)
    for (int r = 0; r < 16; ++r) {
        int row = (r & 3) + 8 * (r >> 2) + 4 * lk + tm * 32;
        int col = tn * 32 + (l & 31);
        float v = acc[r] * inv;
        Gout[row * 64 + col] = v;
        ushort h = f2bf(v);
        int idx = row * 64 + (((col >> 3) ^ (row & 7)) * 8 + (col & 7));
        Ph[idx] = h;
        Pl[idx] = f2bf(v - bf2f(h));
    }
    // squarings (G symmetric: [m][k] plane serves both operands)
    for (int j = 1; j < 5; ++j) {
        __syncthreads();
        floatx16 a2;
        for (int i = 0; i < 16; ++i) a2[i] = 0.f;
        for (int s16 = 0; s16 < 4; ++s16) {
            int gk = 2 * s16 + lk;
            int ai = am * 64 + ((gk ^ (am & 7)) * 8);
            int bi = bn * 64 + ((gk ^ (bn & 7)) * 8);
            short8 ah = *(const short8*)&Ph[ai];
            short8 al = *(const short8*)&Pl[ai];
            short8 bh = *(const short8*)&Ph[bi];
            short8 bl = *(const short8*)&Pl[bi];
            a2 = mfma_bf16(ah, bh, a2);
            a2 = mfma_bf16(al, bh, a2);
            a2 = mfma_bf16(ah, bl, a2);
        }
        __syncthreads();
        for (int r = 0; r < 16; ++r) {
            int row = (r & 3) + 8 * (r >> 2) + 4 * lk + tm * 32;
            int col = tn * 32 + (l & 31);
            float v = a2[r];
            Gout[j * 4096 + row * 64 + col] = v;
            ushort h = f2bf(v);
            int idx = row * 64 + (((col >> 3) ^ (row & 7)) * 8 + (col & 7));
            Ph[idx] = h;
            Pl[idx] = f2bf(v - bf2f(h));
        }
    }
}

// ---------------- big GEMMs: C += A(64x4096) @ B-chunk, split-bf16 MFMA ------
// TB=false: B[k][n] = Bm[k*4096+n]   (X @ Q_S)     -- transposed LDS staging
// TB=true : B[k][n] = Bm[n*4096+k]   (Y @ Q_S^T)   -- direct staging
template <bool TB>
__global__ __launch_bounds__(256) void gemm_kernel(const float* __restrict__ A,
                                                   const float* __restrict__ Bm,
                                                   float* __restrict__ C) {
    __shared__ ushort Ah[64 * 64], Al[64 * 64], Bh[64 * 64], Bl[64 * 64];
    const int t = threadIdx.x;
    const int n0 = blockIdx.x * 64;
    const int kb = blockIdx.y * KCHUNK;
    const int l = t & 63, w = t >> 6;
    const int tm = w & 1, tn = w >> 1;
    const int am = tm * 32 + (l & 31);
    const int bn = tn * 32 + (l & 31);
    const int lk = l >> 5;
    const int sr = t >> 2, sj = t & 3;       // row-staging map
    const int nq = t & 15, kr2 = 2 * (t >> 4);  // transpose-staging map

    floatx16 acc;
    for (int i = 0; i < 16; ++i) acc[i] = 0.f;

    for (int step = 0; step < KCHUNK / 64; ++step) {
        const int k0 = kb + step * 64;
        float4 av[4], bv[4], bva[2], bvb[2];
        for (int s = 0; s < 4; ++s)
            av[s] = *(const float4*)&A[sr * 4096 + k0 + 4 * sj + 16 * s];
        if (TB) {
            for (int s = 0; s < 4; ++s)
                bv[s] = *(const float4*)&Bm[(size_t)(n0 + sr) * 4096 + k0 + 4 * sj + 16 * s];
        } else {
            for (int s = 0; s < 2; ++s) {
                bva[s] = *(const float4*)&Bm[(size_t)(k0 + kr2 + 32 * s) * 4096 + n0 + 4 * nq];
                bvb[s] = *(const float4*)&Bm[(size_t)(k0 + kr2 + 1 + 32 * s) * 4096 + n0 + 4 * nq];
            }
        }
        __syncthreads();  // previous step's frag reads done
        for (int s = 0; s < 4; ++s) {
            int off = 4 * sj + 16 * s;
            int idx = sr * 64 + (((off >> 3) ^ (sr & 7)) * 8 + (off & 7));
            float fa[4] = {av[s].x, av[s].y, av[s].z, av[s].w};
            ushort4 h4, l4;
            ushort* hp = (ushort*)&h4; ushort* lp = (ushort*)&l4;
            for (int i = 0; i < 4; ++i) {
                ushort h = f2bf(fa[i]);
                hp[i] = h; lp[i] = f2bf(fa[i] - bf2f(h));
            }
            *(ushort4*)&Ah[idx] = h4;
            *(ushort4*)&Al[idx] = l4;
        }
        if (TB) {
            for (int s = 0; s < 4; ++s) {
                int off = 4 * sj + 16 * s;
                int idx = sr * 64 + (((off >> 3) ^ (sr & 7)) * 8 + (off & 7));
                float fb[4] = {bv[s].x, bv[s].y, bv[s].z, bv[s].w};
                ushort4 h4, l4;
                ushort* hp = (ushort*)&h4; ushort* lp = (ushort*)&l4;
                for (int i = 0; i < 4; ++i) {
                    ushort h = f2bf(fb[i]);
                    hp[i] = h; lp[i] = f2bf(fb[i] - bf2f(h));
                }
                *(ushort4*)&Bh[idx] = h4;
                *(ushort4*)&Bl[idx] = l4;
            }
        } else {
            for (int s = 0; s < 2; ++s) {
                int k = kr2 + 32 * s;
                float fa[4] = {bva[s].x, bva[s].y, bva[s].z, bva[s].w};
                float fb[4] = {bvb[s].x, bvb[s].y, bvb[s].z, bvb[s].w};
                for (int i = 0; i < 4; ++i) {
                    int n = 4 * nq + i;
                    int idx = n * 64 + (((k >> 3) ^ (n & 7)) * 8 + (k & 7));
                    ushort2 hp2, lp2;
                    hp2.x = f2bf(fa[i]); hp2.y = f2bf(fb[i]);
                    lp2.x = f2bf(fa[i] - bf2f(hp2.x));
                    lp2.y = f2bf(fb[i] - bf2f(hp2.y));
                    *(ushort2*)&Bh[idx] = hp2;
                    *(ushort2*)&Bl[idx] = lp2;
                }
            }
        }
        __syncthreads();
#pragma unroll
        for (int s16 = 0; s16 < 4; ++s16) {
            int gk = 2 * s16 + lk;
            int ai = am * 64 + ((gk ^ (am & 7)) * 8);
            int bi = bn * 64 + ((gk ^ (bn & 7)) * 8);
            short8 ah = *(const short8*)&Ah[ai];
            short8 al = *(const short8*)&Al[ai];
            short8 bh = *(const short8*)&Bh[bi];
            short8 bl = *(const short8*)&Bl[bi];
            acc = mfma_bf16(ah, bh, acc);
            acc = mfma_bf16(al, bh, acc);
            acc = mfma_bf16(ah, bl, acc);
        }
    }
    const int colg = n0 + tn * 32 + (l & 31);
#pragma unroll
    for (int r = 0; r < 16; ++r) {
        int row = (r & 3) + 8 * (r >> 2) + 4 * lk + tm * 32;
        atomicAdd(&C[row * 4096 + colg], acc[r]);
    }
}

// ---------------- solve: T += a^(2^j) * (G_j @ T), j=0..4 -------------------
__global__ __launch_bounds__(256) void solve_kernel(const float* __restrict__ W,
                                                    const float* __restrict__ Gp,
                                                    const float* __restrict__ lam,
                                                    const float* __restrict__ gammap,
                                                    float* __restrict__ Y) {
    __shared__ float Gs[64][68];
    __shared__ float T[64][17];
    const int t = threadIdx.x;
    const int c0 = blockIdx.x * 16;
    for (int e = t; e < 1024; e += 256)
        T[e >> 4][e & 15] = W[(e >> 4) * 4096 + c0 + (e & 15)];
    const int tx = t & 15;
    const int r4 = (t >> 4) * 4;
    const float a = gammap[0] * lam[c0 + tx];
    float s = a;
    for (int j = 0; j < 5; ++j) {
        __syncthreads();
        for (int e = t; e < 4096; e += 256) Gs[e >> 6][e & 63] = Gp[j * 4096 + e];
        __syncthreads();
        float u0 = 0.f, u1 = 0.f, u2 = 0.f, u3 = 0.f;
#pragma unroll 8
        for (int k = 0; k < 64; ++k) {
            const float tv = T[k][tx];
            const float4 g = *(const float4*)&Gs[k][r4];
            u0 += g.x * tv; u1 += g.y * tv; u2 += g.z * tv; u3 += g.w * tv;
        }
        __syncthreads();
        T[r4 + 0][tx] += s * u0;
        T[r4 + 1][tx] += s * u1;
        T[r4 + 2][tx] += s * u2;
        T[r4 + 3][tx] += s * u3;
        s = s * s;
    }
    __syncthreads();
    for (int e = t; e < 1024; e += 256)
        Y[(e >> 4) * 4096 + c0 + (e & 15)] = T[e >> 4][e & 15];
}

extern "C" void kernel_launch(void* const* d_in, const int* in_sizes, int n_in,
                              void* d_out, int out_size, void* d_ws, size_t ws_size,
                              hipStream_t stream) {
    const float* X     = (const float*)d_in[0];
    const float* F     = (const float*)d_in[1];
    const float* Qs    = (const float*)d_in[2];
    const float* lam   = (const float*)d_in[3];
    const float* gamma = (const float*)d_in[4];
    float* Z = (float*)d_out;

    float* W  = (float*)d_ws;
    float* Y  = W + Mdim * Ndim;
    float* Gp = Y + Mdim * Ndim;

    hipMemsetAsync(W, 0, Mdim * Ndim * sizeof(float), stream);
    hipMemsetAsync(Z, 0, Mdim * Ndim * sizeof(float), stream);

    prep_kernel<<<1, 256, 0, stream>>>(F, Gp);
    gemm_kernel<false><<<dim3(Ndim / 64, KSPLIT), 256, 0, stream>>>(X, Qs, W);
    solve_kernel<<<Ndim / 16, 256, 0, stream>>>(W, Gp, lam, gamma, Y);
    gemm_kernel<true><<<dim3(Ndim / 64, KSPLIT), 256, 0, stream>>>(Y, Qs, Z);
}